// Round 1
// baseline (590.486 us; speedup 1.0000x reference)
//
#include <hip/hip_runtime.h>
#include <hip/hip_bf16.h>
#include <cstdint>
#include <cstddef>

// out = x @ weight_real^T + bias
// (magnitude*cos(phase) == real part, identically; weight_imag is dead.)
//
// Fast path: fp32->bf16 pre-convert into d_ws, then m97-style 128x128-tile
// bf16 MFMA GEMM with global_load_lds(width=16) staging.
// Fallback (ws too small): same GEMM core, staging converts fp32->bf16
// in-kernel through registers + ds_write.

#define TILE 128
#define BK 32

typedef short bf16x8 __attribute__((ext_vector_type(8)));  // 8 bf16 in 4 VGPRs
typedef float f32x4 __attribute__((ext_vector_type(4)));

__device__ __forceinline__ unsigned short f2bf(float f) {
  // round-to-nearest-even fp32 -> bf16
  unsigned int x = __float_as_uint(f);
  unsigned int r = x + 0x7FFFu + ((x >> 16) & 1u);
  return (unsigned short)(r >> 16);
}

__global__ void cvt_f32_to_bf16(const float* __restrict__ src,
                                unsigned short* __restrict__ dst, int n8) {
  int i = blockIdx.x * blockDim.x + threadIdx.x;
  int stride = gridDim.x * blockDim.x;
  for (; i < n8; i += stride) {
    float4 a = ((const float4*)src)[2 * i];
    float4 b = ((const float4*)src)[2 * i + 1];
    union { unsigned short u[8]; uint4 v; } o;
    o.u[0] = f2bf(a.x); o.u[1] = f2bf(a.y);
    o.u[2] = f2bf(a.z); o.u[3] = f2bf(a.w);
    o.u[4] = f2bf(b.x); o.u[5] = f2bf(b.y);
    o.u[6] = f2bf(b.z); o.u[7] = f2bf(b.w);
    ((uint4*)dst)[i] = o.v;
  }
}

// A: [M,K] bf16 (K contiguous). B: [N,K] bf16 (K contiguous, i.e. W row-major).
// C: [M,N] fp32. Block = 256 threads = 4 waves (2x2), wave tile 64x64 as 4x4
// MFMA 16x16x32 tiles. LDS tiles unpadded [row][k] (global_load_lds layout).
template <bool DIRECT>
__global__ void gemm_bt_bf16(const unsigned short* __restrict__ Abf,
                             const unsigned short* __restrict__ Bbf,
                             const float* __restrict__ Afp,
                             const float* __restrict__ Bfp,
                             const float* __restrict__ bias,
                             float* __restrict__ C,
                             int M, int N, int K) {
  __shared__ unsigned short Als[TILE * BK];  // 8 KB
  __shared__ unsigned short Bls[TILE * BK];  // 8 KB

  const int tid = threadIdx.x;
  const int wave = tid >> 6;
  const int lane = tid & 63;
  const int lrow = lane & 15;   // fragment row/col index
  const int quad = lane >> 4;   // k-chunk selector (0..3)
  const int mW = (wave >> 1) * 64;
  const int nW = (wave & 1) * 64;
  const int row0 = blockIdx.y * TILE;
  const int col0 = blockIdx.x * TILE;

  f32x4 acc[4][4];
  const f32x4 zero = {0.f, 0.f, 0.f, 0.f};
#pragma unroll
  for (int i = 0; i < 4; ++i)
#pragma unroll
    for (int j = 0; j < 4; ++j) acc[i][j] = zero;

  for (int k0 = 0; k0 < K; k0 += BK) {
    if (DIRECT) {
      // Stage 128x32 bf16 tiles via global_load_lds width=16.
      // Chunk e covers row e>>2, k-cols (e&3)*8..+8; LDS dest is wave-uniform
      // base + lane*16, so LDS layout == [row][k] row-major, unpadded.
#pragma unroll
      for (int c = 0; c < 2; ++c) {
        int e = c * 256 + tid;
        int r = e >> 2;
        int kc = (e & 3) * 8;
        const unsigned short* ga = Abf + (size_t)(row0 + r) * K + k0 + kc;
        const unsigned short* gb = Bbf + (size_t)(col0 + r) * K + k0 + kc;
        unsigned short* la = Als + (size_t)(c * 256 + wave * 64) * 8;
        unsigned short* lb = Bls + (size_t)(c * 256 + wave * 64) * 8;
        __builtin_amdgcn_global_load_lds(
            (const __attribute__((address_space(1))) void*)ga,
            (__attribute__((address_space(3))) void*)la, 16, 0, 0);
        __builtin_amdgcn_global_load_lds(
            (const __attribute__((address_space(1))) void*)gb,
            (__attribute__((address_space(3))) void*)lb, 16, 0, 0);
      }
    } else {
      // Fallback: load fp32, convert in registers, ds_write 16B.
#pragma unroll
      for (int c = 0; c < 2; ++c) {
        int e0 = c * 2048 + tid * 8;  // element index in 128x32 tile
        int r = e0 >> 5;
        int kc = e0 & 31;
        const float* ga = Afp + (size_t)(row0 + r) * K + k0 + kc;
        const float* gb = Bfp + (size_t)(col0 + r) * K + k0 + kc;
        float4 a0 = ((const float4*)ga)[0];
        float4 a1 = ((const float4*)ga)[1];
        float4 b0 = ((const float4*)gb)[0];
        float4 b1 = ((const float4*)gb)[1];
        union { unsigned short u[8]; uint4 v; } oa, ob;
        oa.u[0] = f2bf(a0.x); oa.u[1] = f2bf(a0.y);
        oa.u[2] = f2bf(a0.z); oa.u[3] = f2bf(a0.w);
        oa.u[4] = f2bf(a1.x); oa.u[5] = f2bf(a1.y);
        oa.u[6] = f2bf(a1.z); oa.u[7] = f2bf(a1.w);
        ob.u[0] = f2bf(b0.x); ob.u[1] = f2bf(b0.y);
        ob.u[2] = f2bf(b0.z); ob.u[3] = f2bf(b0.w);
        ob.u[4] = f2bf(b1.x); ob.u[5] = f2bf(b1.y);
        ob.u[6] = f2bf(b1.z); ob.u[7] = f2bf(b1.w);
        *(uint4*)&Als[e0] = oa.v;
        *(uint4*)&Bls[e0] = ob.v;
      }
    }
    __syncthreads();

    // Fragments: A[m=lrow][k=quad*8+j], B[n=lrow][k=quad*8+j]
    bf16x8 af[4], bfr[4];
#pragma unroll
    for (int t = 0; t < 4; ++t) {
      af[t] = *(const bf16x8*)&Als[(mW + t * 16 + lrow) * BK + quad * 8];
      bfr[t] = *(const bf16x8*)&Bls[(nW + t * 16 + lrow) * BK + quad * 8];
    }
#pragma unroll
    for (int mt = 0; mt < 4; ++mt)
#pragma unroll
      for (int nt = 0; nt < 4; ++nt)
        acc[mt][nt] = __builtin_amdgcn_mfma_f32_16x16x32_bf16(
            af[mt], bfr[nt], acc[mt][nt], 0, 0, 0);
    __syncthreads();
  }

  // Epilogue: D[row = quad*4 + r][col = lrow] per 16x16 tile; add bias.
#pragma unroll
  for (int nt = 0; nt < 4; ++nt) {
    int col = col0 + nW + nt * 16 + lrow;
    float bv = bias[col];
#pragma unroll
    for (int mt = 0; mt < 4; ++mt) {
      int rowb = row0 + mW + mt * 16 + quad * 4;
#pragma unroll
      for (int r = 0; r < 4; ++r) {
        C[(size_t)(rowb + r) * N + col] = acc[mt][nt][r] + bv;
      }
    }
  }
}

extern "C" void kernel_launch(void* const* d_in, const int* in_sizes, int n_in,
                              void* d_out, int out_size, void* d_ws, size_t ws_size,
                              hipStream_t stream) {
  const int M = 8192, N = 4096, K = 4096;
  const float* x = (const float*)d_in[0];
  const float* wr = (const float*)d_in[1];
  // d_in[2] (weight_imag) is provably unused: mag*cos(phase) == real.
  const float* bias = (const float*)d_in[3];
  float* out = (float*)d_out;

  const size_t nA = (size_t)M * K;
  const size_t nB = (size_t)N * K;
  dim3 grid(N / TILE, M / TILE);  // 32 x 64 = 2048 blocks

  if (ws_size >= (nA + nB) * sizeof(unsigned short)) {
    unsigned short* xa = (unsigned short*)d_ws;
    unsigned short* wb = xa + nA;
    hipLaunchKernelGGL(cvt_f32_to_bf16, dim3(2048), dim3(256), 0, stream,
                       x, xa, (int)(nA / 8));
    hipLaunchKernelGGL(cvt_f32_to_bf16, dim3(1024), dim3(256), 0, stream,
                       wr, wb, (int)(nB / 8));
    hipLaunchKernelGGL((gemm_bt_bf16<true>), grid, dim3(256), 0, stream,
                       xa, wb, (const float*)nullptr, (const float*)nullptr,
                       bias, out, M, N, K);
  } else {
    hipLaunchKernelGGL((gemm_bt_bf16<false>), grid, dim3(256), 0, stream,
                       (const unsigned short*)nullptr, (const unsigned short*)nullptr,
                       x, wr, bias, out, M, N, K);
  }
}

// Round 2
// 577.141 us; speedup vs baseline: 1.0231x; 1.0231x over previous
//
#include <hip/hip_runtime.h>
#include <hip/hip_bf16.h>
#include <cstdint>
#include <cstddef>

// out = x @ weight_real^T + bias
// (magnitude*cos(phase) == real, identically; weight_imag is dead.)
//
// R2: BK 32->64 (halve barrier count, amortize the vmcnt(0)+s_barrier drain),
// cvt kernels fused into one. GEMM core otherwise the proven m97 structure.

#define TILE 128
#define BK 64

typedef short bf16x8 __attribute__((ext_vector_type(8)));  // 8 bf16 in 4 VGPRs
typedef float f32x4 __attribute__((ext_vector_type(4)));

__device__ __forceinline__ unsigned short f2bf(float f) {
  // round-to-nearest-even fp32 -> bf16
  unsigned int x = __float_as_uint(f);
  unsigned int r = x + 0x7FFFu + ((x >> 16) & 1u);
  return (unsigned short)(r >> 16);
}

// Converts x (nA8 chunks of 8 floats) then wr (nB8 chunks) in one kernel.
__global__ void cvt_both_f32_to_bf16(const float* __restrict__ x,
                                     const float* __restrict__ wr,
                                     unsigned short* __restrict__ xa,
                                     unsigned short* __restrict__ wb,
                                     int nA8, int nB8) {
  int i = blockIdx.x * blockDim.x + threadIdx.x;
  int stride = gridDim.x * blockDim.x;
  int total = nA8 + nB8;
  for (; i < total; i += stride) {
    const float* src; unsigned short* dst; int j;
    if (i < nA8) { src = x;  dst = xa; j = i; }
    else         { src = wr; dst = wb; j = i - nA8; }
    float4 a = ((const float4*)src)[2 * j];
    float4 b = ((const float4*)src)[2 * j + 1];
    union { unsigned short u[8]; uint4 v; } o;
    o.u[0] = f2bf(a.x); o.u[1] = f2bf(a.y);
    o.u[2] = f2bf(a.z); o.u[3] = f2bf(a.w);
    o.u[4] = f2bf(b.x); o.u[5] = f2bf(b.y);
    o.u[6] = f2bf(b.z); o.u[7] = f2bf(b.w);
    ((uint4*)dst)[j] = o.v;
  }
}

// A: [M,K] bf16 (K contiguous). B: [N,K] bf16 (K contiguous, W row-major).
// C: [M,N] fp32. Block = 256 threads = 4 waves (2x2), wave tile 64x64 as 4x4
// MFMA 16x16x32 tiles. LDS tiles unpadded [row][k] (global_load_lds layout).
// BK=64: two K=32 sub-steps per barrier pair.
template <bool DIRECT>
__global__ void gemm_bt_bf16(const unsigned short* __restrict__ Abf,
                             const unsigned short* __restrict__ Bbf,
                             const float* __restrict__ Afp,
                             const float* __restrict__ Bfp,
                             const float* __restrict__ bias,
                             float* __restrict__ C,
                             int M, int N, int K) {
  __shared__ unsigned short Als[TILE * BK];  // 16 KB
  __shared__ unsigned short Bls[TILE * BK];  // 16 KB

  const int tid = threadIdx.x;
  const int wave = tid >> 6;
  const int lane = tid & 63;
  const int lrow = lane & 15;   // fragment row/col index
  const int quad = lane >> 4;   // k-chunk selector (0..3)
  const int mW = (wave >> 1) * 64;
  const int nW = (wave & 1) * 64;
  const int row0 = blockIdx.y * TILE;
  const int col0 = blockIdx.x * TILE;

  f32x4 acc[4][4];
  const f32x4 zero = {0.f, 0.f, 0.f, 0.f};
#pragma unroll
  for (int i = 0; i < 4; ++i)
#pragma unroll
    for (int j = 0; j < 4; ++j) acc[i][j] = zero;

  for (int k0 = 0; k0 < K; k0 += BK) {
    if (DIRECT) {
      // 128x64 bf16 tile = 1024 16B-chunks; 4 rounds x 256 threads.
      // chunk e: row e>>3, k-chunk (e&7)*8. LDS dest = wave-uniform base +
      // lane*16 -> LDS layout [row][k] row-major (128B rows), unpadded.
#pragma unroll
      for (int c = 0; c < 4; ++c) {
        int e = c * 256 + tid;
        int r = e >> 3;
        int kc = (e & 7) * 8;
        const unsigned short* ga = Abf + (size_t)(row0 + r) * K + k0 + kc;
        const unsigned short* gb = Bbf + (size_t)(col0 + r) * K + k0 + kc;
        unsigned short* la = Als + (size_t)(c * 256 + wave * 64) * 8;
        unsigned short* lb = Bls + (size_t)(c * 256 + wave * 64) * 8;
        __builtin_amdgcn_global_load_lds(
            (const __attribute__((address_space(1))) void*)ga,
            (__attribute__((address_space(3))) void*)la, 16, 0, 0);
        __builtin_amdgcn_global_load_lds(
            (const __attribute__((address_space(1))) void*)gb,
            (__attribute__((address_space(3))) void*)lb, 16, 0, 0);
      }
    } else {
      // Fallback: load fp32, convert in registers, ds_write 16B.
#pragma unroll
      for (int c = 0; c < 4; ++c) {
        int e0 = (c * 256 + tid) * 8;  // element index in 128x64 tile
        int r = e0 >> 6;
        int kc = e0 & 63;
        const float* ga = Afp + (size_t)(row0 + r) * K + k0 + kc;
        const float* gb = Bfp + (size_t)(col0 + r) * K + k0 + kc;
        float4 a0 = ((const float4*)ga)[0];
        float4 a1 = ((const float4*)ga)[1];
        float4 b0 = ((const float4*)gb)[0];
        float4 b1 = ((const float4*)gb)[1];
        union { unsigned short u[8]; uint4 v; } oa, ob;
        oa.u[0] = f2bf(a0.x); oa.u[1] = f2bf(a0.y);
        oa.u[2] = f2bf(a0.z); oa.u[3] = f2bf(a0.w);
        oa.u[4] = f2bf(a1.x); oa.u[5] = f2bf(a1.y);
        oa.u[6] = f2bf(a1.z); oa.u[7] = f2bf(a1.w);
        ob.u[0] = f2bf(b0.x); ob.u[1] = f2bf(b0.y);
        ob.u[2] = f2bf(b0.z); ob.u[3] = f2bf(b0.w);
        ob.u[4] = f2bf(b1.x); ob.u[5] = f2bf(b1.y);
        ob.u[6] = f2bf(b1.z); ob.u[7] = f2bf(b1.w);
        *(uint4*)&Als[e0] = oa.v;
        *(uint4*)&Bls[e0] = ob.v;
      }
    }
    __syncthreads();

    // Two K=32 sub-steps. Fragments: A[m=lrow][k=h*32+quad*8+j].
#pragma unroll
    for (int h = 0; h < 2; ++h) {
      bf16x8 af[4], bfr[4];
#pragma unroll
      for (int t = 0; t < 4; ++t) {
        af[t]  = *(const bf16x8*)&Als[(mW + t * 16 + lrow) * BK + h * 32 + quad * 8];
        bfr[t] = *(const bf16x8*)&Bls[(nW + t * 16 + lrow) * BK + h * 32 + quad * 8];
      }
#pragma unroll
      for (int mt = 0; mt < 4; ++mt)
#pragma unroll
        for (int nt = 0; nt < 4; ++nt)
          acc[mt][nt] = __builtin_amdgcn_mfma_f32_16x16x32_bf16(
              af[mt], bfr[nt], acc[mt][nt], 0, 0, 0);
    }
    __syncthreads();
  }

  // Epilogue: D[row = quad*4 + r][col = lrow] per 16x16 tile; add bias.
#pragma unroll
  for (int nt = 0; nt < 4; ++nt) {
    int col = col0 + nW + nt * 16 + lrow;
    float bv = bias[col];
#pragma unroll
    for (int mt = 0; mt < 4; ++mt) {
      int rowb = row0 + mW + mt * 16 + quad * 4;
#pragma unroll
      for (int r = 0; r < 4; ++r) {
        C[(size_t)(rowb + r) * N + col] = acc[mt][nt][r] + bv;
      }
    }
  }
}

extern "C" void kernel_launch(void* const* d_in, const int* in_sizes, int n_in,
                              void* d_out, int out_size, void* d_ws, size_t ws_size,
                              hipStream_t stream) {
  const int M = 8192, N = 4096, K = 4096;
  const float* x = (const float*)d_in[0];
  const float* wr = (const float*)d_in[1];
  // d_in[2] (weight_imag) is provably unused: mag*cos(phase) == real.
  const float* bias = (const float*)d_in[3];
  float* out = (float*)d_out;

  const size_t nA = (size_t)M * K;
  const size_t nB = (size_t)N * K;
  dim3 grid(N / TILE, M / TILE);  // 32 x 64 = 2048 blocks

  if (ws_size >= (nA + nB) * sizeof(unsigned short)) {
    unsigned short* xa = (unsigned short*)d_ws;
    unsigned short* wb = xa + nA;
    hipLaunchKernelGGL(cvt_both_f32_to_bf16, dim3(4096), dim3(256), 0, stream,
                       x, wr, xa, wb, (int)(nA / 8), (int)(nB / 8));
    hipLaunchKernelGGL((gemm_bt_bf16<true>), grid, dim3(256), 0, stream,
                       xa, wb, (const float*)nullptr, (const float*)nullptr,
                       bias, out, M, N, K);
  } else {
    hipLaunchKernelGGL((gemm_bt_bf16<false>), grid, dim3(256), 0, stream,
                       (const unsigned short*)nullptr, (const unsigned short*)nullptr,
                       x, wr, bias, out, M, N, K);
  }
}